// Round 22
// baseline (75.801 us; speedup 1.0000x reference)
//
#include <hip/hip_runtime.h>

#define N_NODES 50000
#define N_EDGES 800000
#define D_IN    128
#define CAP     64      // max degree ~40 for Binomial(800k, 1/50k)

#define NBKT    782     // ceil(50000/64) buckets of 64 nodes (bucket = dst>>6)
#define BCAP    1280    // per-bucket staging cap (mean 1024, sd 32, +8 sigma)
#define EPT     16      // edges per thread in k_split
#define EPB     (256 * EPT)                        // 4096 edges per split block
#define SPLIT_BLOCKS ((N_EDGES + EPB - 1) / EPB)   // 196
#define CVT_BLOCKS   (N_NODES / 8)                 // 6250 (2 rows/wave)

#define NSLC    4       // feature slices of 32 dims; slice plane = 3.2MB (fits 4MB L2)

// ---------------------------------------------------------------------------
// Round 22 = round 21 + FEATURE-SLICED gather (the L3->L2 lever):
//   Xs[slice][node] : 32 dims bf16 = 64B/node/slice; plane = 3.2MB, L2-resident.
//   k_sgather: block=(bucket,slice), slice=blockIdx&3 -> XCD p only touches
//   slice p&3 (round-robin dispatch). Gathers become L2 hits; L3 traffic
//   drops ~105MB -> ~13MB. Same per-edge cache-line count as before.
//   partial[4][N] + k_reduce(sum+selfdot).
//
// ws: gctr 4KB | staging 4MB | cnt 200KB | sorted16 6.4MB | Xs 12.8MB |
//     selfdot 200KB | partial 800KB   (~24.4 MB)
// ---------------------------------------------------------------------------

__device__ __forceinline__ unsigned int f32_to_bf16_rn(float f) {
    unsigned int u = __float_as_uint(f);
    u += 0x7fffu + ((u >> 16) & 1u);      // round-to-nearest-even
    return u >> 16;
}

__global__ __launch_bounds__(256) void k_zero(int* __restrict__ gctr)
{
    int i = blockIdx.x * 256 + threadIdx.x;
    if (i < NBKT) gctr[i] = 0;
}

__global__ __launch_bounds__(256) void k_split_cvt(
    const int*   __restrict__ src,
    const int*   __restrict__ dst,
    int*         __restrict__ gctr,
    unsigned int* __restrict__ staging,
    const float* __restrict__ X,
    const float* __restrict__ W_r,
    const float* __restrict__ b_l,
    unsigned int* __restrict__ Xs,     // sliced bf16 planes (u32 view)
    float*       __restrict__ selfdot)
{
    int b = blockIdx.x;
    if (b < SPLIT_BLOCKS) {
        __shared__ int hist[NBKT];
        __shared__ int base[NBKT];
        int tid = threadIdx.x;
        for (int i = tid; i < NBKT; i += 256) hist[i] = 0;
        __syncthreads();

        int t[EPT], s[EPT], bk[EPT];
        bool ok[EPT];
        const int4* d4 = (const int4*)dst;
        const int4* s4 = (const int4*)src;
        int q0 = b * (EPB / 4) + tid;
#pragma unroll
        for (int k = 0; k < 4; ++k) {
            int q = q0 + (k << 8);                     // int4 index
            bool v = (q * 4) < N_EDGES;                // N_EDGES % 4 == 0
            int qc = v ? q : 0;
            int4 dv = d4[qc];
            int4 sv = s4[qc];
            t[k*4+0] = dv.x; t[k*4+1] = dv.y; t[k*4+2] = dv.z; t[k*4+3] = dv.w;
            s[k*4+0] = sv.x; s[k*4+1] = sv.y; s[k*4+2] = sv.z; s[k*4+3] = sv.w;
            ok[k*4+0] = ok[k*4+1] = ok[k*4+2] = ok[k*4+3] = v;
        }
#pragma unroll
        for (int k = 0; k < EPT; ++k) {
            bk[k] = t[k] >> 6;
            if (ok[k]) atomicAdd(&hist[bk[k]], 1);     // fire-and-forget LDS add
        }
        __syncthreads();
        for (int i = tid; i < NBKT; i += 256) {
            int h = hist[i];
            base[i] = h ? atomicAdd(&gctr[i], h) : 0;  // 1 global atomic/bucket
            hist[i] = 0;                               // reuse as cursor
        }
        __syncthreads();
#pragma unroll
        for (int k = 0; k < EPT; ++k) {
            if (ok[k]) {
                int pos = base[bk[k]] + atomicAdd(&hist[bk[k]], 1);
                if (pos < BCAP)
                    staging[(size_t)bk[k] * BCAP + pos] =
                        ((unsigned int)(t[k] & 63) << 16) | (unsigned int)s[k];
            }
        }
        return;
    }
    // cvt role: 2 rows per wave, float4 per lane; write SLICED layout.
    int wave = ((b - SPLIT_BLOCKS) * 256 + threadIdx.x) >> 6;
    int lane = threadIdx.x & 63;
    int half = lane >> 5;            // 0 or 1
    int sub  = lane & 31;            // covers dims [4*sub, 4*sub+4)
    int row  = wave * 2 + half;
    if (row >= N_NODES) return;

    float4 x = ((const float4*)(X + (size_t)row * D_IN))[sub];
    unsigned int p0 = (f32_to_bf16_rn(x.y) << 16) | f32_to_bf16_rn(x.x);
    unsigned int p1 = (f32_to_bf16_rn(x.w) << 16) | f32_to_bf16_rn(x.z);
    int slice = sub >> 3;            // dims 4*sub -> slice (32 dims each)
    int off   = sub & 7;             // uint2 slot within 64B node row
    ((uint2*)Xs)[((size_t)slice * N_NODES + row) * 8 + off] = make_uint2(p0, p1);

    float4 wr = ((const float4*)W_r)[sub];
    float acc = x.x * wr.x + x.y * wr.y + x.z * wr.z + x.w * wr.w;
#pragma unroll
    for (int off2 = 16; off2; off2 >>= 1)
        acc += __shfl_down(acc, off2, 32);
    if (sub == 0)
        selfdot[row] = acc + b_l[0];
}

// One block per 64-node bucket: LDS per-node segments, int4 write-out.
__global__ __launch_bounds__(256) void k_build(
    const unsigned int* __restrict__ staging,
    const int*   __restrict__ gctr,
    int*         __restrict__ cnt,
    unsigned short* __restrict__ sorted16)
{
    __shared__ __align__(16) unsigned short lbuf[64 * CAP];   // 8 KB
    __shared__ int lcnt[64];
    int b   = blockIdx.x;        // bucket
    int tid = threadIdx.x;
    if (tid < 64) lcnt[tid] = 0;
    __syncthreads();

    int count = gctr[b];
    if (count > BCAP) count = BCAP;
    for (int i = tid; i < count; i += 256) {
        unsigned int rec = staging[(size_t)b * BCAP + i];
        int nlo = rec >> 16;
        int pos = atomicAdd(&lcnt[nlo], 1);
        if (pos < CAP)
            lbuf[nlo * CAP + pos] = (unsigned short)(rec & 0xffffu);
    }
    __syncthreads();

    int nodebase = b << 6;
    if (tid < 64) {
        int node = nodebase + tid;
        if (node < N_NODES) {
            int c = lcnt[tid];
            cnt[node] = c < CAP ? c : CAP;
        }
    }
    int nrows = N_NODES - nodebase;
    if (nrows > 64) nrows = 64;
    int tot128 = nrows * (CAP / 8);              // int4s to copy
    const int4* lb128 = (const int4*)lbuf;
    int4* out128 = (int4*)(sorted16 + (size_t)nodebase * CAP);
    for (int i = tid; i < tot128; i += 256)
        out128[i] = lb128[i];                    // garbage tails never read
}

#define SMAX(mm, uu)                                                  \
    {                                                                 \
        (mm).x = fmaxf((mm).x, __uint_as_float((uu) << 16));          \
        (mm).y = fmaxf((mm).y, __uint_as_float((uu) & 0xffff0000u));  \
    }

// Sliced gather: block = (bucket, slice=blockIdx&3). 4 waves x 16 nodes.
// 16 lanes per neighbor (64B slice row), 4 neighbors per request.
__global__ __launch_bounds__(256) void k_sgather(
    const unsigned short* __restrict__ sorted16,
    const int*   __restrict__ cnt,
    const unsigned int* __restrict__ Xs,
    const float* __restrict__ W_l,
    float*       __restrict__ partial)
{
    __shared__ __align__(16) unsigned short lids[64 * CAP];   // 8 KB
    __shared__ int lcnt[64];
    int slice = blockIdx.x & 3;
    int bkt   = blockIdx.x >> 2;
    int tid   = threadIdx.x;
    int nodebase = bkt << 6;

    // preload bucket id lists (8KB) + counts
    const int4* sids = (const int4*)(sorted16 + (size_t)nodebase * CAP);
    int4* dids = (int4*)lids;
    dids[tid]       = sids[tid];
    dids[tid + 256] = sids[tid + 256];
    if (tid < 64) {
        int node = nodebase + tid;
        lcnt[tid] = (node < N_NODES) ? cnt[node] : 0;
    }
    __syncthreads();

    int wid  = tid >> 6;             // 0..3
    int lane = tid & 63;
    int grp  = lane >> 4;            // neighbor group 0..3
    int d    = lane & 15;            // dword within 64B slice row
    float2 wl = ((const float2*)W_l)[slice * 16 + d];
    unsigned sliceBase = (unsigned)slice * (N_NODES * 16);

#pragma unroll
    for (int j = 0; j < 16; ++j) {
        int li   = (wid << 4) + j;
        int node = nodebase + li;
        if (node >= N_NODES) break;          // wave-uniform (last bucket only)
        int n = lcnt[li];
        const unsigned short* seg = &lids[li * CAP];

        float2 m0 = make_float2(-INFINITY, -INFINITY);
        float2 m1 = m0, m2 = m0, m3 = m0;

        int i = 0;
        for (; i + 16 <= n; i += 16) {       // 4 requests in flight
            int id0 = seg[i +      grp];
            int id1 = seg[i + 4  + grp];
            int id2 = seg[i + 8  + grp];
            int id3 = seg[i + 12 + grp];
            unsigned u0 = Xs[sliceBase + ((unsigned)id0 << 4) + d];
            unsigned u1 = Xs[sliceBase + ((unsigned)id1 << 4) + d];
            unsigned u2 = Xs[sliceBase + ((unsigned)id2 << 4) + d];
            unsigned u3 = Xs[sliceBase + ((unsigned)id3 << 4) + d];
            SMAX(m0, u0) SMAX(m1, u1) SMAX(m2, u2) SMAX(m3, u3)
        }
        if (i + 8 <= n) {
            int id0 = seg[i + grp];
            int id1 = seg[i + 4 + grp];
            unsigned u0 = Xs[sliceBase + ((unsigned)id0 << 4) + d];
            unsigned u1 = Xs[sliceBase + ((unsigned)id1 << 4) + d];
            SMAX(m0, u0) SMAX(m1, u1)
            i += 8;
        }
        if (i + 4 <= n) {
            int id0 = seg[i + grp];
            unsigned u0 = Xs[sliceBase + ((unsigned)id0 << 4) + d];
            SMAX(m0, u0)
            i += 4;
        }
        if (i < n) {                          // tail < 4: sentinel-guarded
            bool v = (i + grp) < n;
            int idt = v ? (int)seg[i + grp] : 0;
            unsigned ut = v ? Xs[sliceBase + ((unsigned)idt << 4) + d]
                            : 0xFF7FFF7Fu;    // two most-negative-finite bf16
            SMAX(m0, ut)
        }
        m0.x = fmaxf(fmaxf(m0.x, m1.x), fmaxf(m2.x, m3.x));
        m0.y = fmaxf(fmaxf(m0.y, m1.y), fmaxf(m2.y, m3.y));
        // cross-group max (groups differ by lane bits 4,5)
        m0.x = fmaxf(m0.x, __shfl_xor(m0.x, 16));
        m0.y = fmaxf(m0.y, __shfl_xor(m0.y, 16));
        m0.x = fmaxf(m0.x, __shfl_xor(m0.x, 32));
        m0.y = fmaxf(m0.y, __shfl_xor(m0.y, 32));

        float p = m0.x * wl.x + m0.y * wl.y;  // partial dot over this slice
#pragma unroll
        for (int off = 8; off; off >>= 1)
            p += __shfl_down(p, off);
        if (lane == 0)
            partial[(size_t)slice * N_NODES + node] = (n > 0) ? p : 0.0f;
    }
}

__global__ __launch_bounds__(256) void k_reduce(
    const float* __restrict__ partial,
    const float* __restrict__ selfdot,
    float*       __restrict__ out)
{
    int i = blockIdx.x * 256 + threadIdx.x;
    if (i < N_NODES)
        out[i] = partial[i] + partial[N_NODES + i] + partial[2 * N_NODES + i]
               + partial[3 * N_NODES + i] + selfdot[i];
}

extern "C" void kernel_launch(void* const* d_in, const int* in_sizes, int n_in,
                              void* d_out, int out_size, void* d_ws, size_t ws_size,
                              hipStream_t stream)
{
    const float* X   = (const float*)d_in[0];   // [N_NODES, D_IN]
    const float* W_l = (const float*)d_in[1];   // [1, D_IN]
    const float* b_l = (const float*)d_in[2];   // [1]
    const float* W_r = (const float*)d_in[3];   // [1, D_IN]
    const int*   ei  = (const int*)d_in[4];     // [2, N_EDGES]
    const int*   src = ei;
    const int*   dst = ei + N_EDGES;

    int* gctr = (int*)d_ws;                                            // 4 KB
    unsigned int* staging = (unsigned int*)(gctr + 1024);              // 4.0 MB
    int* cnt = (int*)(staging + (size_t)NBKT * BCAP);                  // 200 KB
    unsigned short* sorted16 = (unsigned short*)(cnt + N_NODES);       // 6.4 MB
    unsigned int* Xs = (unsigned int*)(sorted16 + (size_t)N_NODES * CAP); // 12.8 MB
    float* selfdot = (float*)(Xs + (size_t)NSLC * N_NODES * 16);       // 200 KB
    float* partial = selfdot + N_NODES;                                // 800 KB
    float* out = (float*)d_out;

    k_zero<<<(NBKT + 255) / 256, 256, 0, stream>>>(gctr);
    k_split_cvt<<<SPLIT_BLOCKS + CVT_BLOCKS, 256, 0, stream>>>(
        src, dst, gctr, staging, X, W_r, b_l, Xs, selfdot);
    k_build<<<NBKT, 256, 0, stream>>>(staging, gctr, cnt, sorted16);
    k_sgather<<<NBKT * NSLC, 256, 0, stream>>>(sorted16, cnt, Xs, W_l, partial);
    k_reduce<<<(N_NODES + 255) / 256, 256, 0, stream>>>(partial, selfdot, out);
}

// Round 23
// 57.690 us; speedup vs baseline: 1.3139x; 1.3139x over previous
//
#include <hip/hip_runtime.h>

#define N_NODES 50000
#define N_EDGES 800000
#define D_IN    128
#define CAP     64      // max degree ~40 for Binomial(800k, 1/50k)

#define NBKT    782     // ceil(50000/64) buckets of 64 nodes (bucket = dst>>6)
#define BCAP    1280    // per-bucket staging cap (mean 1024, sd 32, +8 sigma)
#define EPT     16      // edges per thread in k_split
#define EPB     (256 * EPT)                        // 4096 edges per split block
#define SPLIT_BLOCKS ((N_EDGES + EPB - 1) / EPB)   // 196
#define CVT_BLOCKS   (N_NODES / 8)                 // 6250 (2 rows/wave)

// ---------------------------------------------------------------------------
// Round 23 = round 20 (57.0us, measured best) + Phase-A load/barrier overlap.
// Round 22 post-mortem: feature-slicing cut FETCH 105->28MB but the gather is
// REQUEST-RATE bound, not L3-BW bound (VALUBusy 63%, dur 2x worse) — full-row
// 256B gathers are the right shape. This pipeline is the floor structure.
//
// ws: gctr[1024] 4KB | staging[782*1280] u32 4MB | Xh[N*128] u16 12.8MB |
//     selfdot[N] f32 200KB
// ---------------------------------------------------------------------------

__device__ __forceinline__ unsigned int f32_to_bf16_rn(float f) {
    unsigned int u = __float_as_uint(f);
    u += 0x7fffu + ((u >> 16) & 1u);      // round-to-nearest-even
    return u >> 16;
}

__global__ __launch_bounds__(256) void k_zero(int* __restrict__ gctr)
{
    int i = blockIdx.x * 256 + threadIdx.x;
    if (i < NBKT) gctr[i] = 0;
}

__global__ __launch_bounds__(256) void k_split_cvt(
    const int*   __restrict__ src,
    const int*   __restrict__ dst,
    int*         __restrict__ gctr,
    unsigned int* __restrict__ staging,
    const float* __restrict__ X,
    const float* __restrict__ W_r,
    const float* __restrict__ b_l,
    unsigned short* __restrict__ Xh,
    float*       __restrict__ selfdot)
{
    int b = blockIdx.x;
    if (b < SPLIT_BLOCKS) {
        __shared__ int hist[NBKT];
        __shared__ int base[NBKT];
        int tid = threadIdx.x;
        for (int i = tid; i < NBKT; i += 256) hist[i] = 0;
        __syncthreads();

        int t[EPT], s[EPT], bk[EPT];
        bool ok[EPT];
        const int4* d4 = (const int4*)dst;
        const int4* s4 = (const int4*)src;
        int q0 = b * (EPB / 4) + tid;
#pragma unroll
        for (int k = 0; k < 4; ++k) {
            int q = q0 + (k << 8);                     // int4 index
            bool v = (q * 4) < N_EDGES;                // N_EDGES % 4 == 0
            int qc = v ? q : 0;
            int4 dv = d4[qc];
            int4 sv = s4[qc];
            t[k*4+0] = dv.x; t[k*4+1] = dv.y; t[k*4+2] = dv.z; t[k*4+3] = dv.w;
            s[k*4+0] = sv.x; s[k*4+1] = sv.y; s[k*4+2] = sv.z; s[k*4+3] = sv.w;
            ok[k*4+0] = ok[k*4+1] = ok[k*4+2] = ok[k*4+3] = v;
        }
#pragma unroll
        for (int k = 0; k < EPT; ++k) {
            bk[k] = t[k] >> 6;
            if (ok[k]) atomicAdd(&hist[bk[k]], 1);     // fire-and-forget LDS add
        }
        __syncthreads();
        for (int i = tid; i < NBKT; i += 256) {
            int h = hist[i];
            base[i] = h ? atomicAdd(&gctr[i], h) : 0;  // 1 global atomic/bucket
            hist[i] = 0;                               // reuse as cursor
        }
        __syncthreads();
#pragma unroll
        for (int k = 0; k < EPT; ++k) {
            if (ok[k]) {
                int pos = base[bk[k]] + atomicAdd(&hist[bk[k]], 1);
                if (pos < BCAP)
                    staging[(size_t)bk[k] * BCAP + pos] =
                        ((unsigned int)(t[k] & 63) << 16) | (unsigned int)s[k];
            }
        }
        return;
    }
    // cvt role: 2 rows per wave, float4 per lane (16B), width-32 reduce.
    int wave = ((b - SPLIT_BLOCKS) * 256 + threadIdx.x) >> 6;
    int lane = threadIdx.x & 63;
    int half = lane >> 5;            // 0 or 1
    int sub  = lane & 31;
    int row  = wave * 2 + half;
    if (row >= N_NODES) return;

    float4 x = ((const float4*)(X + (size_t)row * D_IN))[sub];
    unsigned int p0 = (f32_to_bf16_rn(x.y) << 16) | f32_to_bf16_rn(x.x);
    unsigned int p1 = (f32_to_bf16_rn(x.w) << 16) | f32_to_bf16_rn(x.z);
    ((uint2*)Xh)[row * 32 + sub] = make_uint2(p0, p1);

    float4 wr = ((const float4*)W_r)[sub];
    float acc = x.x * wr.x + x.y * wr.y + x.z * wr.z + x.w * wr.w;
#pragma unroll
    for (int off = 16; off; off >>= 1)
        acc += __shfl_down(acc, off, 32);
    if (sub == 0)
        selfdot[row] = acc + b_l[0];
}

#define GLOAD(uu, ss)  uu = Xu[((unsigned)(ss) << 6) | (unsigned)lane];
#define GMAX(mm, uu)                                                  \
    {                                                                 \
        (mm).x = fmaxf((mm).x, __uint_as_float((uu) << 16));          \
        (mm).y = fmaxf((mm).y, __uint_as_float((uu) & 0xffff0000u));  \
    }
#define GATHER(mm, ss)                                                \
    { unsigned int u_; GLOAD(u_, ss) GMAX(mm, u_) }

// Fused build+aggregate: one block per 64-node bucket, 1024 threads.
// Phase A: staging loads issued BEFORE the lcnt-init barrier (overlap).
// Phase B: 16 waves x 4 nodes; ids via LDS broadcast; 16-deep MLP gather.
__global__ __launch_bounds__(1024, 8) void k_bagg(
    const unsigned int* __restrict__ staging,
    const int*   __restrict__ gctr,
    const unsigned short* __restrict__ Xh,
    const float* __restrict__ W_l,
    const float* __restrict__ selfdot,
    float*       __restrict__ out)
{
    __shared__ unsigned short lbuf[64 * CAP];   // 8 KB
    __shared__ int lcnt[64];
    int b   = blockIdx.x;
    int tid = threadIdx.x;

    // issue staging loads first — they don't depend on LDS state
    int count = gctr[b];
    if (count > BCAP) count = BCAP;
    bool v0 = tid < count;
    bool v1 = tid + 1024 < count;
    unsigned int r0 = 0, r1 = 0;
    if (v0) r0 = staging[(size_t)b * BCAP + tid];
    if (v1) r1 = staging[(size_t)b * BCAP + tid + 1024];

    if (tid < 64) lcnt[tid] = 0;
    __syncthreads();

    if (v0) {
        int nlo = r0 >> 16;
        int pos = atomicAdd(&lcnt[nlo], 1);
        if (pos < CAP) lbuf[nlo * CAP + pos] = (unsigned short)(r0 & 0xffffu);
    }
    if (v1) {
        int nlo = r1 >> 16;
        int pos = atomicAdd(&lcnt[nlo], 1);
        if (pos < CAP) lbuf[nlo * CAP + pos] = (unsigned short)(r1 & 0xffffu);
    }
    __syncthreads();

    // Phase B: 16 waves x 4 nodes each
    int wid  = tid >> 6;             // 0..15
    int lane = tid & 63;
    float2 wl = ((const float2*)W_l)[lane];
    const unsigned int* Xu = (const unsigned int*)Xh;
    int nodebase = b << 6;

#pragma unroll
    for (int j = 0; j < 4; ++j) {
        int li   = (wid << 2) + j;           // 0..63
        int node = nodebase + li;
        if (node >= N_NODES) continue;       // only last bucket
        float sd = selfdot[node];            // prefetch
        int n = lcnt[li];
        if (n > CAP) n = CAP;
        const unsigned short* seg = &lbuf[li * CAP];   // uniform -> broadcast

        float2 m[8];
#pragma unroll
        for (int k = 0; k < 8; ++k) m[k] = make_float2(-INFINITY, -INFINITY);

        int i = 0;
        for (; i + 16 <= n; i += 16) {
            int sr[16];
#pragma unroll
            for (int k = 0; k < 16; ++k) sr[k] = seg[i + k];
            unsigned int u[16];
#pragma unroll
            for (int k = 0; k < 16; ++k) GLOAD(u[k], sr[k])   // 16 in flight
#pragma unroll
            for (int k = 0; k < 16; ++k) GMAX(m[k & 7], u[k])
        }
        if (i + 8 <= n) {
            int sr[8];
#pragma unroll
            for (int k = 0; k < 8; ++k) sr[k] = seg[i + k];
            unsigned int u[8];
#pragma unroll
            for (int k = 0; k < 8; ++k) GLOAD(u[k], sr[k])
#pragma unroll
            for (int k = 0; k < 8; ++k) GMAX(m[k], u[k])
            i += 8;
        }
        if (i + 4 <= n) {
            GATHER(m[0], seg[i + 0]) GATHER(m[1], seg[i + 1])
            GATHER(m[2], seg[i + 2]) GATHER(m[3], seg[i + 3])
            i += 4;
        }
        if (i + 2 <= n) {
            GATHER(m[0], seg[i + 0]) GATHER(m[1], seg[i + 1])
            i += 2;
        }
        if (i < n) {
            GATHER(m[0], seg[i])
        }
#pragma unroll
        for (int k = 4; k; k >>= 1)
#pragma unroll
            for (int q = 0; q < k; ++q) {
                m[q].x = fmaxf(m[q].x, m[q + k].x);
                m[q].y = fmaxf(m[q].y, m[q + k].y);
            }
        if (n == 0) { m[0].x = 0.0f; m[0].y = 0.0f; }   // segment_max empty fill

        float acc = m[0].x * wl.x + m[0].y * wl.y;
#pragma unroll
        for (int off = 32; off; off >>= 1)
            acc += __shfl_down(acc, off);
        if (lane == 0)
            out[node] = acc + sd;
    }
}

extern "C" void kernel_launch(void* const* d_in, const int* in_sizes, int n_in,
                              void* d_out, int out_size, void* d_ws, size_t ws_size,
                              hipStream_t stream)
{
    const float* X   = (const float*)d_in[0];   // [N_NODES, D_IN]
    const float* W_l = (const float*)d_in[1];   // [1, D_IN]
    const float* b_l = (const float*)d_in[2];   // [1]
    const float* W_r = (const float*)d_in[3];   // [1, D_IN]
    const int*   ei  = (const int*)d_in[4];     // [2, N_EDGES]
    const int*   src = ei;
    const int*   dst = ei + N_EDGES;

    int* gctr = (int*)d_ws;                                         // 4 KB (1024 ints)
    unsigned int* staging = (unsigned int*)(gctr + 1024);           // 4.0 MB
    unsigned short* Xh = (unsigned short*)(staging + (size_t)NBKT * BCAP); // 12.8 MB
    float* selfdot = (float*)(Xh + (size_t)N_NODES * D_IN);         // 200 KB
    float* out = (float*)d_out;

    k_zero<<<(NBKT + 255) / 256, 256, 0, stream>>>(gctr);
    k_split_cvt<<<SPLIT_BLOCKS + CVT_BLOCKS, 256, 0, stream>>>(
        src, dst, gctr, staging, X, W_r, b_l, Xh, selfdot);
    k_bagg<<<NBKT, 1024, 0, stream>>>(staging, gctr, Xh, W_l, selfdot, out);
}